// Round 3
// baseline (351.692 us; speedup 1.0000x reference)
//
#include <hip/hip_runtime.h>
#include <hip/hip_bf16.h>

typedef __bf16 bf16_t;
typedef __bf16 bf16x2 __attribute__((ext_vector_type(2)));

#define DIM 128

// ---------- edge-index dtype detector ----------
// If edge_index is int64 (little-endian, values < 2^31), every odd int32 word
// of the buffer is 0. Sample 256 odd words; all zero => int64 (flag=1).
__global__ void k_detect(const int* __restrict__ EI, int* __restrict__ flag, int e) {
    __shared__ int any;
    if (threadIdx.x == 0) any = 0;
    __syncthreads();
    long step = e / 256; if (step < 1) step = 1;
    long p = (long)threadIdx.x * step; if (p >= e) p = e - 1;
    if (EI[2 * p + 1] != 0) atomicOr(&any, 1);
    __syncthreads();
    if (threadIdx.x == 0) *flag = (any ? 0 : 1);
}

// ---------- degree / norm ----------
__global__ void k_zero(int* __restrict__ c, int n) {
    int i = blockIdx.x * 256 + threadIdx.x;
    if (i < n) c[i] = 0;
}

__global__ void k_count(const int* __restrict__ EI, const int* __restrict__ flag,
                        int* __restrict__ cnt, int e) {
    int i = blockIdx.x * 256 + threadIdx.x;
    if (i >= e) return;
    int f = *flag;
    int d = f ? EI[2 * ((long)e + i)] : EI[e + i];
    atomicAdd(&cnt[d], 1);
}

__global__ void k_dinv(const int* __restrict__ cnt, float* __restrict__ dinv, int n) {
    int i = blockIdx.x * 256 + threadIdx.x;
    if (i < n) dinv[i] = rsqrtf((float)(cnt[i] + 1));   // +1 self loop; always > 0
}

// ---------- exclusive scan (3 kernels) ----------
__global__ __launch_bounds__(1024) void k_reduce(const int* __restrict__ cnt, int* __restrict__ sums, int n) {
    __shared__ int s[1024];
    int t = threadIdx.x;
    int g = blockIdx.x * 1024 + t;
    s[t] = (g < n) ? cnt[g] : 0;
    __syncthreads();
    for (int h = 512; h > 0; h >>= 1) {
        if (t < h) s[t] += s[t + h];
        __syncthreads();
    }
    if (t == 0) sums[blockIdx.x] = s[0];
}

__global__ void k_scan_sums(int* __restrict__ sums, int nc) {   // 1 block, 64 threads, nc<=64
    int l = threadIdx.x;
    int v = (l < nc) ? sums[l] : 0;
    int orig = v;
    for (int off = 1; off < 64; off <<= 1) {
        int u = __shfl_up(v, off);
        if (l >= off) v += u;
    }
    if (l < nc) sums[l] = v - orig;   // exclusive chunk offsets
}

__global__ __launch_bounds__(1024) void k_scan_blocks(const int* __restrict__ cnt,
        const int* __restrict__ chunk_off, int* __restrict__ rowptr, int n) {
    __shared__ int buf[1024];
    int t = threadIdx.x;
    int g = blockIdx.x * 1024 + t;
    int v = (g < n) ? cnt[g] : 0;
    buf[t] = v;
    __syncthreads();
    for (int off = 1; off < 1024; off <<= 1) {
        int add = (t >= off) ? buf[t - off] : 0;
        __syncthreads();
        buf[t] += add;
        __syncthreads();
    }
    int excl = buf[t] - v + chunk_off[blockIdx.x];
    if (g < n) rowptr[g] = excl;
}

__global__ void k_cursor(int* __restrict__ rowptr, int* __restrict__ cur, int n, int e) {
    int i = blockIdx.x * 256 + threadIdx.x;
    if (i < n) cur[i] = rowptr[i];
    if (i == 0) rowptr[n] = e;
}

__global__ void k_scatter(const int* __restrict__ EI, const int* __restrict__ flag,
        int* __restrict__ cur, int* __restrict__ col, int e) {
    int i = blockIdx.x * 256 + threadIdx.x;
    if (i >= e) return;
    int f = *flag;
    long li = i;
    int s = f ? EI[2 * li] : EI[li];
    int d = f ? EI[2 * ((long)e + li)] : EI[e + li];
    int pos = atomicAdd(&cur[d], 1);
    col[pos] = s;
}

// ---------- GEMM: H[M,128](bf16) = A[M,128](fp32) @ W[128,128](fp32) ----------
// Vector-ALU fp32 (no fp32 MFMA on CDNA4). W + 16-row X tile staged in LDS.
// Thread t: cols c=2*(t&63), rows rg*4..rg*4+4 where rg = wave index.
__global__ __launch_bounds__(256) void k_gemm(const float* __restrict__ A,
        const float* __restrict__ W, bf16_t* __restrict__ H, int M) {
    __shared__ float Ws[DIM][DIM];   // 64 KB
    __shared__ float Xs[16][DIM];    // 8 KB
    int t = threadIdx.x;
    const float4* W4 = (const float4*)W;
    float4* Ws4 = (float4*)&Ws[0][0];
#pragma unroll
    for (int i = 0; i < 16; i++) Ws4[t + 256 * i] = W4[t + 256 * i];   // 4096 float4
    long row0 = (long)blockIdx.x * 16;                                  // M % 16 == 0
    const float4* A4 = (const float4*)(A + row0 * DIM);
    float4* Xs4 = (float4*)&Xs[0][0];
#pragma unroll
    for (int i = 0; i < 2; i++) Xs4[t + 256 * i] = A4[t + 256 * i];     // 512 float4
    __syncthreads();

    int c = (t & 63) * 2;
    int rg = t >> 6;                 // wave index -> Xs row broadcast within wave
    float acc[4][2] = {{0.f,0.f},{0.f,0.f},{0.f,0.f},{0.f,0.f}};
    for (int k = 0; k < DIM; k++) {
        float2 wv = *(const float2*)&Ws[k][c];
#pragma unroll
        for (int r = 0; r < 4; r++) {
            float x = Xs[rg * 4 + r][k];
            acc[r][0] += x * wv.x;
            acc[r][1] += x * wv.y;
        }
    }
#pragma unroll
    for (int r = 0; r < 4; r++) {
        bf16x2 o;
        o.x = (bf16_t)acc[r][0];
        o.y = (bf16_t)acc[r][1];
        *(bf16x2*)&H[(row0 + rg * 4 + r) * DIM + c] = o;
    }
}

// ---------- aggregation: wave per node, lane owns 2 columns ----------
__global__ __launch_bounds__(256) void k_agg(const bf16_t* __restrict__ H,
        const int* __restrict__ rowptr, const int* __restrict__ col,
        const float* __restrict__ dinv,
        const float* __restrict__ bias, float* __restrict__ out,
        int n, int do_relu) {
    int lane = threadIdx.x & 63;
    int i = blockIdx.x * 4 + (threadIdx.x >> 6);
    if (i >= n) return;
    float d = dinv[i];
    bf16x2 hi = *(const bf16x2*)(H + (long)i * DIM + lane * 2);
    float s0 = d * (float)hi.x, s1 = d * (float)hi.y;   // self-loop term dinv[i]*H[i]
    int beg = rowptr[i], end = rowptr[i + 1];
    for (int j = beg; j < end; j++) {
        int s = col[j];
        float w = dinv[s];
        bf16x2 hs = *(const bf16x2*)(H + (long)s * DIM + lane * 2);
        s0 += w * (float)hs.x;
        s1 += w * (float)hs.y;
    }
    float r0 = d * s0 + bias[lane * 2];
    float r1 = d * s1 + bias[lane * 2 + 1];
    if (do_relu) { r0 = fmaxf(r0, 0.f); r1 = fmaxf(r1, 0.f); }
    float2 o; o.x = r0; o.y = r1;
    *(float2*)(out + (long)i * DIM + lane * 2) = o;
}

extern "C" void kernel_launch(void* const* d_in, const int* in_sizes, int n_in,
                              void* d_out, int out_size, void* d_ws, size_t ws_size,
                              hipStream_t stream) {
    const float* X  = (const float*)d_in[0];
    const int*   EI = (const int*)d_in[1];
    const float* W1 = (const float*)d_in[2];
    const float* B1 = (const float*)d_in[3];
    const float* W2 = (const float*)d_in[4];
    const float* B2 = (const float*)d_in[5];
    float* OUT = (float*)d_out;

    const int N = in_sizes[0] / DIM;   // 50000
    const int E = in_sizes[1] / 2;     // 600000
    (void)n_in; (void)out_size; (void)ws_size;

    // ---- workspace layout (~16 MB; X1 staged in d_out as fp32) ----
    char* w = (char*)d_ws;
    auto alloc = [&](size_t bytes) -> char* {
        char* p = w;
        w += (bytes + 255) & ~(size_t)255;
        return p;
    };
    int*    cnt    = (int*)alloc((size_t)N * 4);          // reused as scatter cursor
    int*    rowptr = (int*)alloc((size_t)(N + 1) * 4);
    int*    csums  = (int*)alloc(64 * 4);
    int*    flag   = (int*)alloc(4);
    float*  dinv   = (float*)alloc((size_t)N * 4);
    int*    col    = (int*)alloc((size_t)E * 4);
    bf16_t* H      = (bf16_t*)alloc((size_t)N * DIM * 2); // 12.8 MB, bf16 internal
    float*  X1     = OUT;                                  // stage layer-1 output in d_out

    int gN = (N + 255) / 256, gE = (E + 255) / 256;
    int nc = (N + 1023) / 1024;        // 49 (<=64 for the wave scan)

    k_detect<<<1, 256, 0, stream>>>(EI, flag, E);
    k_zero<<<gN, 256, 0, stream>>>(cnt, N);
    k_count<<<gE, 256, 0, stream>>>(EI, flag, cnt, E);
    k_dinv<<<gN, 256, 0, stream>>>(cnt, dinv, N);
    k_reduce<<<nc, 1024, 0, stream>>>(cnt, csums, N);
    k_scan_sums<<<1, 64, 0, stream>>>(csums, nc);
    k_scan_blocks<<<nc, 1024, 0, stream>>>(cnt, csums, rowptr, N);
    k_cursor<<<gN, 256, 0, stream>>>(rowptr, cnt /*cur*/, N, E);
    k_scatter<<<gE, 256, 0, stream>>>(EI, flag, cnt /*cur*/, col, E);

    int gG = N / 16;                   // 3125 blocks (N % 16 == 0)
    int gA = (N + 3) / 4;              // 4 nodes per block (wave per node)

    k_gemm<<<gG, 256, 0, stream>>>(X, W1, H, N);
    k_agg<<<gA, 256, 0, stream>>>(H, rowptr, col, dinv, B1, X1, N, 1);
    k_gemm<<<gG, 256, 0, stream>>>(X1, W2, H, N);
    k_agg<<<gA, 256, 0, stream>>>(H, rowptr, col, dinv, B2, OUT, N, 0);
}

// Round 4
// 241.693 us; speedup vs baseline: 1.4551x; 1.4551x over previous
//
#include <hip/hip_runtime.h>
#include <hip/hip_bf16.h>

typedef __bf16 bf16_t;
typedef __bf16 bf16x8 __attribute__((ext_vector_type(8)));
typedef float f32x4 __attribute__((ext_vector_type(4)));

#define DIM 128

// ---------- zero degree counters + detect edge-index dtype ----------
// int64 little-endian with values < 2^31 => every odd int32 word is 0.
__global__ void k_pre(const int* __restrict__ EI, int* __restrict__ cnt,
                      int* __restrict__ flag, int n, int e) {
    int i = blockIdx.x * 256 + threadIdx.x;
    if (i < n) cnt[i] = 0;
    if (blockIdx.x == 0) {
        __shared__ int any;
        if (threadIdx.x == 0) any = 0;
        __syncthreads();
        long step = e / 256; if (step < 1) step = 1;
        long p = (long)threadIdx.x * step; if (p >= e) p = e - 1;
        if (EI[2 * p + 1] != 0) atomicOr(&any, 1);
        __syncthreads();
        if (threadIdx.x == 0) *flag = (any ? 0 : 1);   // 1 => int64
    }
}

__global__ void k_count(const int* __restrict__ EI, const int* __restrict__ flag,
                        int* __restrict__ cnt, int e) {
    int i = blockIdx.x * 256 + threadIdx.x;
    if (i >= e) return;
    int f = *flag;
    int d = f ? EI[2 * ((long)e + i)] : EI[e + i];
    atomicAdd(&cnt[d], 1);
}

// ---------- block reduce (for scan) + dinv ----------
__global__ __launch_bounds__(1024) void k_reduce(const int* __restrict__ cnt,
        int* __restrict__ sums, float* __restrict__ dinv, int n) {
    __shared__ int s[1024];
    int t = threadIdx.x;
    int g = blockIdx.x * 1024 + t;
    int v = (g < n) ? cnt[g] : 0;
    if (g < n) dinv[g] = rsqrtf((float)(v + 1));   // +1 self loop; always > 0
    s[t] = v;
    __syncthreads();
    for (int h = 512; h > 0; h >>= 1) {
        if (t < h) s[t] += s[t + h];
        __syncthreads();
    }
    if (t == 0) sums[blockIdx.x] = s[0];
}

__global__ void k_scan_sums(int* __restrict__ sums, int nc) {   // 1 block, 64 threads, nc<=64
    int l = threadIdx.x;
    int v = (l < nc) ? sums[l] : 0;
    int orig = v;
    for (int off = 1; off < 64; off <<= 1) {
        int u = __shfl_up(v, off);
        if (l >= off) v += u;
    }
    if (l < nc) sums[l] = v - orig;   // exclusive chunk offsets
}

__global__ __launch_bounds__(1024) void k_scan_blocks(const int* __restrict__ cnt,
        const int* __restrict__ chunk_off, int* __restrict__ rowptr,
        int* __restrict__ cur, int n) {
    __shared__ int buf[1024];
    int t = threadIdx.x;
    int g = blockIdx.x * 1024 + t;
    int v = (g < n) ? cnt[g] : 0;
    buf[t] = v;
    __syncthreads();
    for (int off = 1; off < 1024; off <<= 1) {
        int add = (t >= off) ? buf[t - off] : 0;
        __syncthreads();
        buf[t] += add;
        __syncthreads();
    }
    int excl = buf[t] - v + chunk_off[blockIdx.x];
    if (g < n) { rowptr[g] = excl; cur[g] = excl; }
    if (g == n - 1) rowptr[n] = excl + v;          // total = E
}

__global__ void k_scatter(const int* __restrict__ EI, const int* __restrict__ flag,
        int* __restrict__ cur, int* __restrict__ col, int e) {
    int i = blockIdx.x * 256 + threadIdx.x;
    if (i >= e) return;
    int f = *flag;
    long li = i;
    int s = f ? EI[2 * li] : EI[li];
    int d = f ? EI[2 * ((long)e + li)] : EI[e + li];
    int pos = atomicAdd(&cur[d], 1);
    col[pos] = s;
}

// ---------- GEMM: H[M,128](bf16) = A[M,128](fp32) @ W[128,128](fp32) ----------
// bf16 MFMA with hi/lo split (3-term) => ~fp32 accuracy, ~3x MFMA flops (cheap).
// 4 waves x 16 rows = 64 rows/block. W^T staged in LDS as hi/lo bf16, stride 136.
__global__ __launch_bounds__(256) void k_gemm(const float* __restrict__ A,
        const float* __restrict__ W, bf16_t* __restrict__ H, int M) {
    __shared__ __align__(16) bf16_t WTh[128][136];
    __shared__ __align__(16) bf16_t WTl[128][136];
    int tid = threadIdx.x;
    for (int idx = tid; idx < 128 * 128; idx += 256) {
        int k = idx >> 7, nn = idx & 127;
        float wv = W[idx];
        bf16_t h = (bf16_t)wv;
        WTh[nn][k] = h;
        WTl[nn][k] = (bf16_t)(wv - (float)h);
    }
    __syncthreads();

    int wave = tid >> 6, lane = tid & 63;
    long row_base = ((long)blockIdx.x * 4 + wave) * 16;
    if (row_base >= M) return;                     // M % 16 == 0, no partial tiles
    int n16 = lane & 15, quad = lane >> 4;

    // A fragment: A[m = lane&15][k = quad*8 + kc*32 + j], split hi/lo
    bf16x8 a_hi[4], a_lo[4];
    const float* arow = A + (row_base + n16) * DIM + quad * 8;
#pragma unroll
    for (int kc = 0; kc < 4; kc++) {
        float4 p0 = *(const float4*)(arow + kc * 32);
        float4 p1 = *(const float4*)(arow + kc * 32 + 4);
        float v[8] = {p0.x, p0.y, p0.z, p0.w, p1.x, p1.y, p1.z, p1.w};
#pragma unroll
        for (int j = 0; j < 8; j++) {
            bf16_t h = (bf16_t)v[j];
            a_hi[kc][j] = h;
            a_lo[kc][j] = (bf16_t)(v[j] - (float)h);
        }
    }

#pragma unroll
    for (int nt = 0; nt < 8; nt++) {
        f32x4 acc = {0.f, 0.f, 0.f, 0.f};
#pragma unroll
        for (int kc = 0; kc < 4; kc++) {
            bf16x8 bh = *(const bf16x8*)(&WTh[nt * 16 + n16][kc * 32 + quad * 8]);
            bf16x8 bl = *(const bf16x8*)(&WTl[nt * 16 + n16][kc * 32 + quad * 8]);
            acc = __builtin_amdgcn_mfma_f32_16x16x32_bf16(a_hi[kc], bh, acc, 0, 0, 0);
            acc = __builtin_amdgcn_mfma_f32_16x16x32_bf16(a_lo[kc], bh, acc, 0, 0, 0);
            acc = __builtin_amdgcn_mfma_f32_16x16x32_bf16(a_hi[kc], bl, acc, 0, 0, 0);
        }
        // C/D: col = lane&15, row = quad*4 + reg
        bf16_t* hrow = H + (row_base + quad * 4) * DIM + nt * 16 + n16;
#pragma unroll
        for (int r = 0; r < 4; r++) hrow[(long)r * DIM] = (bf16_t)acc[r];
    }
}

// ---------- aggregation: 4 nodes per wave (16 lanes/node, bf16x8 = 16B/lane) ----------
// 8 independent H-row gathers in flight per wave (4 nodes x unroll 2).
__global__ __launch_bounds__(256) void k_agg(const bf16_t* __restrict__ H,
        const int* __restrict__ rowptr, const int* __restrict__ col,
        const float* __restrict__ dinv, const float* __restrict__ bias,
        float* __restrict__ out, int n, int do_relu) {
    int lane = threadIdx.x & 63;
    int wave = threadIdx.x >> 6;
    int sub = lane >> 4;          // node within wave
    int sl  = lane & 15;          // lane within node: cols sl*8 .. sl*8+7
    int i = (blockIdx.x * 4 + wave) * 4 + sub;
    bool act = (i < n);
    float acc[8] = {0.f, 0.f, 0.f, 0.f, 0.f, 0.f, 0.f, 0.f};
    float d = 0.f;
    int beg = 0, deg = 0;
    if (act) {
        d = dinv[i];
        beg = rowptr[i];
        deg = rowptr[i + 1] - beg;
        bf16x8 hs = *(const bf16x8*)(H + (long)i * DIM + sl * 8);
#pragma unroll
        for (int q = 0; q < 8; q++) acc[q] = d * (float)hs[q];   // self-loop term
    }
    int j = 0;
    for (; j + 2 <= deg; j += 2) {
        int s0 = col[beg + j], s1 = col[beg + j + 1];
        float w0 = dinv[s0], w1 = dinv[s1];
        bf16x8 h0 = *(const bf16x8*)(H + (long)s0 * DIM + sl * 8);
        bf16x8 h1 = *(const bf16x8*)(H + (long)s1 * DIM + sl * 8);
#pragma unroll
        for (int q = 0; q < 8; q++) acc[q] += w0 * (float)h0[q] + w1 * (float)h1[q];
    }
    if (j < deg) {
        int s0 = col[beg + j];
        float w0 = dinv[s0];
        bf16x8 h0 = *(const bf16x8*)(H + (long)s0 * DIM + sl * 8);
#pragma unroll
        for (int q = 0; q < 8; q++) acc[q] += w0 * (float)h0[q];
    }
    if (act) {
        float4 b0 = *(const float4*)(bias + sl * 8);
        float4 b1 = *(const float4*)(bias + sl * 8 + 4);
        float r[8];
        r[0] = d * acc[0] + b0.x; r[1] = d * acc[1] + b0.y;
        r[2] = d * acc[2] + b0.z; r[3] = d * acc[3] + b0.w;
        r[4] = d * acc[4] + b1.x; r[5] = d * acc[5] + b1.y;
        r[6] = d * acc[6] + b1.z; r[7] = d * acc[7] + b1.w;
        if (do_relu) {
#pragma unroll
            for (int q = 0; q < 8; q++) r[q] = fmaxf(r[q], 0.f);
        }
        float* op = out + (long)i * DIM + sl * 8;
        *(float4*)op       = make_float4(r[0], r[1], r[2], r[3]);
        *(float4*)(op + 4) = make_float4(r[4], r[5], r[6], r[7]);
    }
}

extern "C" void kernel_launch(void* const* d_in, const int* in_sizes, int n_in,
                              void* d_out, int out_size, void* d_ws, size_t ws_size,
                              hipStream_t stream) {
    const float* X  = (const float*)d_in[0];
    const int*   EI = (const int*)d_in[1];
    const float* W1 = (const float*)d_in[2];
    const float* B1 = (const float*)d_in[3];
    const float* W2 = (const float*)d_in[4];
    const float* B2 = (const float*)d_in[5];
    float* OUT = (float*)d_out;

    const int N = in_sizes[0] / DIM;   // 50000
    const int E = in_sizes[1] / 2;     // 600000
    (void)n_in; (void)out_size; (void)ws_size;

    // ---- workspace layout (~16 MB; X1 staged in d_out as fp32) ----
    char* w = (char*)d_ws;
    auto alloc = [&](size_t bytes) -> char* {
        char* p = w;
        w += (bytes + 255) & ~(size_t)255;
        return p;
    };
    int*    cnt    = (int*)alloc((size_t)N * 4);
    int*    cur    = (int*)alloc((size_t)N * 4);
    int*    rowptr = (int*)alloc((size_t)(N + 1) * 4);
    int*    csums  = (int*)alloc(64 * 4);
    int*    flag   = (int*)alloc(4);
    float*  dinv   = (float*)alloc((size_t)N * 4);
    int*    col    = (int*)alloc((size_t)E * 4);
    bf16_t* H      = (bf16_t*)alloc((size_t)N * DIM * 2); // 12.8 MB, bf16 internal
    float*  X1     = OUT;                                  // stage layer-1 output in d_out

    int gN = (N + 255) / 256, gE = (E + 255) / 256;
    int nc = (N + 1023) / 1024;        // 49 (<=64 for the wave scan)

    k_pre<<<gN, 256, 0, stream>>>(EI, cnt, flag, N, E);
    k_count<<<gE, 256, 0, stream>>>(EI, flag, cnt, E);
    k_reduce<<<nc, 1024, 0, stream>>>(cnt, csums, dinv, N);
    k_scan_sums<<<1, 64, 0, stream>>>(csums, nc);
    k_scan_blocks<<<nc, 1024, 0, stream>>>(cnt, csums, rowptr, cur, N);
    k_scatter<<<gE, 256, 0, stream>>>(EI, flag, cur, col, E);

    int gG = (N + 63) / 64;            // 64 rows per block (4 waves x 16 rows)
    int gA = (N + 15) / 16;            // 16 nodes per block (4 waves x 4 nodes)

    k_gemm<<<gG, 256, 0, stream>>>(X, W1, H, N);
    k_agg<<<gA, 256, 0, stream>>>(H, rowptr, col, dinv, B1, X1, N, 1);
    k_gemm<<<gG, 256, 0, stream>>>(X1, W2, H, N);
    k_agg<<<gA, 256, 0, stream>>>(H, rowptr, col, dinv, B2, OUT, N, 0);
}

// Round 5
// 237.725 us; speedup vs baseline: 1.4794x; 1.0167x over previous
//
#include <hip/hip_runtime.h>
#include <hip/hip_bf16.h>

typedef __bf16 bf16_t;
typedef __bf16 bf16x8 __attribute__((ext_vector_type(8)));
typedef float f32x4 __attribute__((ext_vector_type(4)));

#define DIM 128

// ---------- zero degree counters + detect edge-index dtype ----------
// int64 little-endian with values < 2^31 => every odd int32 word is 0.
__global__ void k_pre(const int* __restrict__ EI, int* __restrict__ cnt,
                      int* __restrict__ flag, int n, int e) {
    int i = blockIdx.x * 256 + threadIdx.x;
    if (i < n) cnt[i] = 0;
    if (blockIdx.x == 0) {
        __shared__ int any;
        if (threadIdx.x == 0) any = 0;
        __syncthreads();
        long step = e / 256; if (step < 1) step = 1;
        long p = (long)threadIdx.x * step; if (p >= e) p = e - 1;
        if (EI[2 * p + 1] != 0) atomicOr(&any, 1);
        __syncthreads();
        if (threadIdx.x == 0) *flag = (any ? 0 : 1);   // 1 => int64
    }
}

__global__ void k_count(const int* __restrict__ EI, const int* __restrict__ flag,
                        int* __restrict__ cnt, int e) {
    int i = blockIdx.x * 256 + threadIdx.x;
    if (i >= e) return;
    int f = *flag;
    int d = f ? EI[2 * ((long)e + i)] : EI[e + i];
    atomicAdd(&cnt[d], 1);
}

// ---------- block reduce (for scan) + dinv ----------
__global__ __launch_bounds__(1024) void k_reduce(const int* __restrict__ cnt,
        int* __restrict__ sums, float* __restrict__ dinv, int n) {
    __shared__ int s[1024];
    int t = threadIdx.x;
    int g = blockIdx.x * 1024 + t;
    int v = (g < n) ? cnt[g] : 0;
    if (g < n) dinv[g] = rsqrtf((float)(v + 1));   // +1 self loop; always > 0
    s[t] = v;
    __syncthreads();
    for (int h = 512; h > 0; h >>= 1) {
        if (t < h) s[t] += s[t + h];
        __syncthreads();
    }
    if (t == 0) sums[blockIdx.x] = s[0];
}

__global__ void k_scan_sums(int* __restrict__ sums, int nc) {   // 1 block, 64 threads, nc<=64
    int l = threadIdx.x;
    int v = (l < nc) ? sums[l] : 0;
    int orig = v;
    for (int off = 1; off < 64; off <<= 1) {
        int u = __shfl_up(v, off);
        if (l >= off) v += u;
    }
    if (l < nc) sums[l] = v - orig;   // exclusive chunk offsets
}

__global__ __launch_bounds__(1024) void k_scan_blocks(const int* __restrict__ cnt,
        const int* __restrict__ chunk_off, int* __restrict__ rowptr,
        int* __restrict__ cur, int n) {
    __shared__ int buf[1024];
    int t = threadIdx.x;
    int g = blockIdx.x * 1024 + t;
    int v = (g < n) ? cnt[g] : 0;
    buf[t] = v;
    __syncthreads();
    for (int off = 1; off < 1024; off <<= 1) {
        int add = (t >= off) ? buf[t - off] : 0;
        __syncthreads();
        buf[t] += add;
        __syncthreads();
    }
    int excl = buf[t] - v + chunk_off[blockIdx.x];
    if (g < n) { rowptr[g] = excl; cur[g] = excl; }
    if (g == n - 1) rowptr[n] = excl + v;          // total = E
}

__global__ void k_scatter(const int* __restrict__ EI, const int* __restrict__ flag,
        int* __restrict__ cur, int* __restrict__ col, int e) {
    int i = blockIdx.x * 256 + threadIdx.x;
    if (i >= e) return;
    int f = *flag;
    long li = i;
    int s = f ? EI[2 * li] : EI[li];
    int d = f ? EI[2 * ((long)e + li)] : EI[e + li];
    int pos = atomicAdd(&cur[d], 1);
    col[pos] = s;
}

// ---------- GEMM (fp32 A): H[M,128](bf16) = dinv[row] * (A @ W) ----------
// bf16 MFMA with hi/lo split on A and W (3-term) => ~fp32 accuracy.
// 4 waves x 16 rows = 64 rows/block. W^T staged in LDS hi/lo, stride 136.
__global__ __launch_bounds__(256) void k_gemm_f32(const float* __restrict__ A,
        const float* __restrict__ W, const float* __restrict__ dinv,
        bf16_t* __restrict__ H, int M) {
    __shared__ __align__(16) bf16_t WTh[128][136];
    __shared__ __align__(16) bf16_t WTl[128][136];
    int tid = threadIdx.x;
    for (int idx = tid; idx < 128 * 128; idx += 256) {
        int k = idx >> 7, nn = idx & 127;
        float wv = W[idx];
        bf16_t h = (bf16_t)wv;
        WTh[nn][k] = h;
        WTl[nn][k] = (bf16_t)(wv - (float)h);
    }
    __syncthreads();

    int wave = tid >> 6, lane = tid & 63;
    long row_base = ((long)blockIdx.x * 4 + wave) * 16;
    if (row_base >= M) return;                     // M % 16 == 0
    int n16 = lane & 15, quad = lane >> 4;

    bf16x8 a_hi[4], a_lo[4];
    const float* arow = A + (row_base + n16) * DIM + quad * 8;
#pragma unroll
    for (int kc = 0; kc < 4; kc++) {
        float4 p0 = *(const float4*)(arow + kc * 32);
        float4 p1 = *(const float4*)(arow + kc * 32 + 4);
        float v[8] = {p0.x, p0.y, p0.z, p0.w, p1.x, p1.y, p1.z, p1.w};
#pragma unroll
        for (int j = 0; j < 8; j++) {
            bf16_t h = (bf16_t)v[j];
            a_hi[kc][j] = h;
            a_lo[kc][j] = (bf16_t)(v[j] - (float)h);
        }
    }

    float dr[4];
#pragma unroll
    for (int r = 0; r < 4; r++) dr[r] = dinv[row_base + quad * 4 + r];

#pragma unroll
    for (int nt = 0; nt < 8; nt++) {
        f32x4 acc = {0.f, 0.f, 0.f, 0.f};
#pragma unroll
        for (int kc = 0; kc < 4; kc++) {
            bf16x8 bh = *(const bf16x8*)(&WTh[nt * 16 + n16][kc * 32 + quad * 8]);
            bf16x8 bl = *(const bf16x8*)(&WTl[nt * 16 + n16][kc * 32 + quad * 8]);
            acc = __builtin_amdgcn_mfma_f32_16x16x32_bf16(a_hi[kc], bh, acc, 0, 0, 0);
            acc = __builtin_amdgcn_mfma_f32_16x16x32_bf16(a_lo[kc], bh, acc, 0, 0, 0);
            acc = __builtin_amdgcn_mfma_f32_16x16x32_bf16(a_hi[kc], bl, acc, 0, 0, 0);
        }
        bf16_t* hrow = H + (row_base + quad * 4) * DIM + nt * 16 + n16;
#pragma unroll
        for (int r = 0; r < 4; r++) hrow[(long)r * DIM] = (bf16_t)(dr[r] * acc[r]);
    }
}

// ---------- GEMM (bf16 A): H = dinv[row] * (A @ W), hi/lo on W only (2-term) ----------
__global__ __launch_bounds__(256) void k_gemm_b16(const bf16_t* __restrict__ A,
        const float* __restrict__ W, const float* __restrict__ dinv,
        bf16_t* __restrict__ H, int M) {
    __shared__ __align__(16) bf16_t WTh[128][136];
    __shared__ __align__(16) bf16_t WTl[128][136];
    int tid = threadIdx.x;
    for (int idx = tid; idx < 128 * 128; idx += 256) {
        int k = idx >> 7, nn = idx & 127;
        float wv = W[idx];
        bf16_t h = (bf16_t)wv;
        WTh[nn][k] = h;
        WTl[nn][k] = (bf16_t)(wv - (float)h);
    }
    __syncthreads();

    int wave = tid >> 6, lane = tid & 63;
    long row_base = ((long)blockIdx.x * 4 + wave) * 16;
    if (row_base >= M) return;
    int n16 = lane & 15, quad = lane >> 4;

    bf16x8 a[4];
    const bf16_t* arow = A + (row_base + n16) * DIM + quad * 8;
#pragma unroll
    for (int kc = 0; kc < 4; kc++) a[kc] = *(const bf16x8*)(arow + kc * 32);

    float dr[4];
#pragma unroll
    for (int r = 0; r < 4; r++) dr[r] = dinv[row_base + quad * 4 + r];

#pragma unroll
    for (int nt = 0; nt < 8; nt++) {
        f32x4 acc = {0.f, 0.f, 0.f, 0.f};
#pragma unroll
        for (int kc = 0; kc < 4; kc++) {
            bf16x8 bh = *(const bf16x8*)(&WTh[nt * 16 + n16][kc * 32 + quad * 8]);
            bf16x8 bl = *(const bf16x8*)(&WTl[nt * 16 + n16][kc * 32 + quad * 8]);
            acc = __builtin_amdgcn_mfma_f32_16x16x32_bf16(a[kc], bh, acc, 0, 0, 0);
            acc = __builtin_amdgcn_mfma_f32_16x16x32_bf16(a[kc], bl, acc, 0, 0, 0);
        }
        bf16_t* hrow = H + (row_base + quad * 4) * DIM + nt * 16 + n16;
#pragma unroll
        for (int r = 0; r < 4; r++) hrow[(long)r * DIM] = (bf16_t)(dr[r] * acc[r]);
    }
}

// ---------- aggregation: 4 nodes/wave (16 lanes/node, bf16x8 = 16B/lane) ----------
// H is pre-scaled by dinv[src], so inner loop = col gather -> row gather -> add.
// Unroll x4 => 16 independent H-row gathers in flight per wave.
// mode 0: fp32 out, no relu.  mode 1: bf16 out, relu.
__global__ __launch_bounds__(256) void k_agg(const bf16_t* __restrict__ H,
        const int* __restrict__ rowptr, const int* __restrict__ col,
        const float* __restrict__ dinv, const float* __restrict__ bias,
        float* __restrict__ outf, bf16_t* __restrict__ outb,
        int n, int mode) {
    int lane = threadIdx.x & 63;
    int wave = threadIdx.x >> 6;
    int sub = lane >> 4;          // node within wave
    int sl  = lane & 15;          // 16 lanes/node: cols sl*8 .. sl*8+7
    int i = (blockIdx.x * 4 + wave) * 4 + sub;
    bool act = (i < n);
    float acc[8] = {0.f, 0.f, 0.f, 0.f, 0.f, 0.f, 0.f, 0.f};
    float d = 0.f;
    int beg = 0, deg = 0;
    if (act) {
        d = dinv[i];
        beg = rowptr[i];
        deg = rowptr[i + 1] - beg;
        bf16x8 hs = *(const bf16x8*)(H + (long)i * DIM + sl * 8);   // self: dinv[i]*h[i]
#pragma unroll
        for (int q = 0; q < 8; q++) acc[q] = (float)hs[q];
    }
    int j = 0;
    for (; j + 4 <= deg; j += 4) {
        int s0 = col[beg + j],     s1 = col[beg + j + 1];
        int s2 = col[beg + j + 2], s3 = col[beg + j + 3];
        bf16x8 h0 = *(const bf16x8*)(H + (long)s0 * DIM + sl * 8);
        bf16x8 h1 = *(const bf16x8*)(H + (long)s1 * DIM + sl * 8);
        bf16x8 h2 = *(const bf16x8*)(H + (long)s2 * DIM + sl * 8);
        bf16x8 h3 = *(const bf16x8*)(H + (long)s3 * DIM + sl * 8);
#pragma unroll
        for (int q = 0; q < 8; q++)
            acc[q] += ((float)h0[q] + (float)h1[q]) + ((float)h2[q] + (float)h3[q]);
    }
    for (; j < deg; j++) {
        int s0 = col[beg + j];
        bf16x8 h0 = *(const bf16x8*)(H + (long)s0 * DIM + sl * 8);
#pragma unroll
        for (int q = 0; q < 8; q++) acc[q] += (float)h0[q];
    }
    if (act) {
        float4 b0 = *(const float4*)(bias + sl * 8);
        float4 b1 = *(const float4*)(bias + sl * 8 + 4);
        float r[8];
        r[0] = d * acc[0] + b0.x; r[1] = d * acc[1] + b0.y;
        r[2] = d * acc[2] + b0.z; r[3] = d * acc[3] + b0.w;
        r[4] = d * acc[4] + b1.x; r[5] = d * acc[5] + b1.y;
        r[6] = d * acc[6] + b1.z; r[7] = d * acc[7] + b1.w;
        if (mode == 1) {
#pragma unroll
            for (int q = 0; q < 8; q++) r[q] = fmaxf(r[q], 0.f);
            bf16x8 o;
#pragma unroll
            for (int q = 0; q < 8; q++) o[q] = (bf16_t)r[q];
            *(bf16x8*)(outb + (long)i * DIM + sl * 8) = o;
        } else {
            float* op = outf + (long)i * DIM + sl * 8;
            *(float4*)op       = make_float4(r[0], r[1], r[2], r[3]);
            *(float4*)(op + 4) = make_float4(r[4], r[5], r[6], r[7]);
        }
    }
}

extern "C" void kernel_launch(void* const* d_in, const int* in_sizes, int n_in,
                              void* d_out, int out_size, void* d_ws, size_t ws_size,
                              hipStream_t stream) {
    const float* X  = (const float*)d_in[0];
    const int*   EI = (const int*)d_in[1];
    const float* W1 = (const float*)d_in[2];
    const float* B1 = (const float*)d_in[3];
    const float* W2 = (const float*)d_in[4];
    const float* B2 = (const float*)d_in[5];
    float* OUT = (float*)d_out;

    const int N = in_sizes[0] / DIM;   // 50000
    const int E = in_sizes[1] / 2;     // 600000
    (void)n_in; (void)out_size; (void)ws_size;

    // ---- workspace layout (~29 MB) ----
    char* w = (char*)d_ws;
    auto alloc = [&](size_t bytes) -> char* {
        char* p = w;
        w += (bytes + 255) & ~(size_t)255;
        return p;
    };
    int*    cnt    = (int*)alloc((size_t)N * 4);
    int*    cur    = (int*)alloc((size_t)N * 4);
    int*    rowptr = (int*)alloc((size_t)(N + 1) * 4);
    int*    csums  = (int*)alloc(64 * 4);
    int*    flag   = (int*)alloc(4);
    float*  dinv   = (float*)alloc((size_t)N * 4);
    int*    col    = (int*)alloc((size_t)E * 4);
    bf16_t* H      = (bf16_t*)alloc((size_t)N * DIM * 2); // 12.8 MB, pre-scaled by dinv
    bf16_t* X1b    = (bf16_t*)alloc((size_t)N * DIM * 2); // 12.8 MB, layer-1 activations

    int gN = (N + 255) / 256, gE = (E + 255) / 256;
    int nc = (N + 1023) / 1024;        // 49 (<=64 for the wave scan)

    k_pre<<<gN, 256, 0, stream>>>(EI, cnt, flag, N, E);
    k_count<<<gE, 256, 0, stream>>>(EI, flag, cnt, E);
    k_reduce<<<nc, 1024, 0, stream>>>(cnt, csums, dinv, N);
    k_scan_sums<<<1, 64, 0, stream>>>(csums, nc);
    k_scan_blocks<<<nc, 1024, 0, stream>>>(cnt, csums, rowptr, cur, N);
    k_scatter<<<gE, 256, 0, stream>>>(EI, flag, cur, col, E);

    int gG = (N + 63) / 64;            // 64 rows per block (4 waves x 16 rows)
    int gA = (N + 15) / 16;            // 16 nodes per block (4 waves x 4 nodes)

    k_gemm_f32<<<gG, 256, 0, stream>>>(X,   W1, dinv, H, N);
    k_agg<<<gA, 256, 0, stream>>>(H, rowptr, col, dinv, B1, nullptr, X1b, N, 1);
    k_gemm_b16<<<gG, 256, 0, stream>>>(X1b, W2, dinv, H, N);
    k_agg<<<gA, 256, 0, stream>>>(H, rowptr, col, dinv, B2, OUT, nullptr, N, 0);
}